// Round 1
// baseline (103.673 us; speedup 1.0000x reference)
//
#include <hip/hip_runtime.h>

// Problem constants: B=2, T=8, NQ=128, NK=128, DIM_IN=64, DIM_OUT=256
// C = 2*log2(e): folds tanh's e^{2x} into exp2, and softmax's exp into exp2.
#define C_TANH 2.8853900817779268f

// q1[b*128 + q][d] = C * (query[b,q,:] @ Wq[:,d])
__global__ __launch_bounds__(256) void qproj_kernel(
    const float* __restrict__ query, const float* __restrict__ Wq,
    float* __restrict__ q1) {
  int row = blockIdx.x;   // B*NQ = 256 rows
  int d   = threadIdx.x;  // 256 output dims
  __shared__ float qrow[64];
  if (d < 64) qrow[d] = query[row * 64 + d];
  __syncthreads();
  float acc = 0.f;
#pragma unroll
  for (int i = 0; i < 64; ++i) acc += qrow[i] * Wq[i * 256 + d];
  q1[row * 256 + d] = acc * C_TANH;  // coalesced store
}

// k2[bt][d][k] = C * (keys[bt,k,:] @ Wk[:,d] + bk[d])   (transposed layout!)
// One block per (bt, d): Wk/bk reads are block-uniform -> scalar loads;
// keys reads per-thread contiguous (vectorized); store coalesced across k.
__global__ __launch_bounds__(128) void kproj_kernel(
    const float* __restrict__ keys, const float* __restrict__ Wk,
    const float* __restrict__ bk, float* __restrict__ k2) {
  int bid = blockIdx.x;   // bt*256 + d, 16*256 = 4096 blocks
  int bt  = bid >> 8;
  int d   = bid & 255;
  int k   = threadIdx.x;  // 128
  const float* krow = keys + (bt * 128 + k) * 64;
  float acc = bk[d];
#pragma unroll
  for (int i = 0; i < 64; ++i) acc += krow[i] * Wk[i * 256 + d];
  k2[(bt * 256 + d) * 128 + k] = acc * C_TANH;
}

// One block = 2 q-rows of the same (b,t). Thread (r,k) owns score[g0+r][k].
// logits_k = -2 * sum_d v_d / (1 + exp2(q'_d + k'_dk))   (Sum v_d dropped:
// constant per row, softmax shift-invariant). Softmax done in exp2 domain.
__global__ __launch_bounds__(256) void score_kernel(
    const float* __restrict__ q1, const float* __restrict__ v,
    const float* __restrict__ k2, float* __restrict__ out) {
  __shared__ float2 qv[2][256];  // {q', v} packed -> one ds_read_b64/iter
  __shared__ float redm[4], reds[4];
  int tid = threadIdx.x;
  int r   = tid >> 7;   // which of the 2 q-rows (wave-uniform)
  int k   = tid & 127;  // key index (lane-contiguous)
  int wid = tid >> 6;
  int g0  = blockIdx.x * 2;          // global (b,t,q) row pair base, 2048 rows
  int bt  = g0 >> 7;                 // b*T + t
  int b   = g0 >> 10;
  int q1base = b * 128 + (g0 & 127); // q1 row index (q1 has only B*NQ rows)

  for (int idx = tid; idx < 512; idx += 256) {
    int r2 = idx >> 8;
    int d  = idx & 255;
    qv[r2][d] = make_float2(q1[(q1base + r2) * 256 + d], v[d]);
  }
  __syncthreads();

  const float* kp = k2 + bt * 256 * 128 + k;
  float acc = 0.f;
#pragma unroll 8
  for (int d = 0; d < 256; ++d) {
    float2 t = qv[r][d];                       // LDS broadcast
    float x  = t.x + kp[d * 128];              // coalesced global (L2-hot)
    float e  = __builtin_amdgcn_exp2f(x);
    acc += t.y * __builtin_amdgcn_rcpf(1.0f + e);
  }
  float s = -C_TANH * acc;  // logit already scaled by log2(e) for exp2 softmax

  // row max: wave butterfly then combine the row's 2 waves via LDS
  float m = s;
#pragma unroll
  for (int off = 32; off > 0; off >>= 1) m = fmaxf(m, __shfl_xor(m, off, 64));
  if ((tid & 63) == 0) redm[wid] = m;
  __syncthreads();
  float rowm = fmaxf(redm[r * 2], redm[r * 2 + 1]);

  float e = __builtin_amdgcn_exp2f(s - rowm);
  float ssum = e;
#pragma unroll
  for (int off = 32; off > 0; off >>= 1) ssum += __shfl_xor(ssum, off, 64);
  if ((tid & 63) == 0) reds[wid] = ssum;
  __syncthreads();
  float tot = reds[r * 2] + reds[r * 2 + 1];

  out[(g0 + r) * 128 + k] = e * __builtin_amdgcn_rcpf(tot);  // coalesced
}

extern "C" void kernel_launch(void* const* d_in, const int* in_sizes, int n_in,
                              void* d_out, int out_size, void* d_ws, size_t ws_size,
                              hipStream_t stream) {
  const float* query = (const float*)d_in[0];  // [2,128,64]
  const float* keys  = (const float*)d_in[1];  // [2,8,128,64]
  const float* Wq    = (const float*)d_in[2];  // [64,256]
  const float* Wk    = (const float*)d_in[3];  // [64,256]
  const float* bk    = (const float*)d_in[4];  // [256]
  const float* v     = (const float*)d_in[5];  // [256]
  float* out = (float*)d_out;                  // [2,8,128,128]

  float* ws = (float*)d_ws;
  float* q1 = ws;            // 2*128*256        = 65536 floats (256 KB)
  float* k2 = ws + 65536;    // 2*8*256*128      = 524288 floats (2 MB)

  qproj_kernel<<<256, 256, 0, stream>>>(query, Wq, q1);
  kproj_kernel<<<4096, 128, 0, stream>>>(keys, Wk, bk, k2);
  score_kernel<<<1024, 256, 0, stream>>>(q1, v, k2, out);
}

// Round 2
// 91.603 us; speedup vs baseline: 1.1318x; 1.1318x over previous
//
#include <hip/hip_runtime.h>

// Problem constants: B=2, T=8, NQ=128, NK=128, DIM_IN=64, DIM_OUT=256
// C = 2*log2(e): folds tanh's e^{2x} into exp2, and softmax's exp into exp2.
#define C_TANH 2.8853900817779268f

// k2[bt][d][k] = C * (keys[bt,k,:] @ Wk[:,d] + bk[d])   (transposed layout)
// Block = (bt, key-group-of-8): 16*16 = 256 blocks, 256 threads = d.
// Key rows staged via ONE coalesced float4 load; Wk reads lane-coalesced;
// inner loop reads key rows as wave-uniform ds_read_b128 broadcasts.
// This replaces the old 256B-inter-lane-stride pattern (64 cache lines per
// wave load -> serialized L1 transactions) that dominated round-1 runtime.
__global__ __launch_bounds__(256) void kproj_kernel(
    const float* __restrict__ keys, const float* __restrict__ Wk,
    const float* __restrict__ bk, float* __restrict__ k2) {
  int bid = blockIdx.x;
  int bt  = bid >> 4;       // 0..15
  int kg  = bid & 15;       // key group of 8
  int d   = threadIdx.x;    // 256 output dims
  __shared__ float4 krows4[128];  // 8 key rows x 64 floats = 2 KB

  if (threadIdx.x < 128)
    krows4[threadIdx.x] =
        ((const float4*)(keys + bt * 8192 + kg * 512))[threadIdx.x];
  __syncthreads();

  float acc[8];
  float bias = bk[d];
#pragma unroll
  for (int kk = 0; kk < 8; ++kk) acc[kk] = bias;

#pragma unroll 4
  for (int i4 = 0; i4 < 16; ++i4) {
    // Wk[(4*i4+j)*256 + d]: coalesced across lanes (d)
    float wa = Wk[(i4 * 4 + 0) * 256 + d];
    float wb = Wk[(i4 * 4 + 1) * 256 + d];
    float wc = Wk[(i4 * 4 + 2) * 256 + d];
    float wd = Wk[(i4 * 4 + 3) * 256 + d];
#pragma unroll
    for (int kk = 0; kk < 8; ++kk) {
      float4 kr = krows4[kk * 16 + i4];  // wave-uniform LDS broadcast (b128)
      acc[kk] = fmaf(kr.x, wa, acc[kk]);
      acc[kk] = fmaf(kr.y, wb, acc[kk]);
      acc[kk] = fmaf(kr.z, wc, acc[kk]);
      acc[kk] = fmaf(kr.w, wd, acc[kk]);
    }
  }
#pragma unroll
  for (int kk = 0; kk < 8; ++kk)
    k2[(bt * 256 + d) * 128 + kg * 8 + kk] = acc[kk] * C_TANH;
}

// One block = 2 q-rows of the same (b,t). Thread (r,k) owns score[g0+r][k].
// q-projection is computed inline (32K MACs/block, trivial), removing the
// separate qproj kernel and its global roundtrip.
// logits_k = -2 * sum_d v_d / (1 + exp2(q'_d + k'_dk))   (Sum v_d dropped:
// constant per row, softmax shift-invariant). Softmax done in exp2 domain.
__global__ __launch_bounds__(256) void score_kernel(
    const float* __restrict__ query, const float* __restrict__ Wq,
    const float* __restrict__ v, const float* __restrict__ k2,
    float* __restrict__ out) {
  __shared__ float2 qv[2][256];  // {q', v} packed -> one ds_read_b64/iter
  __shared__ float qrow[2][64];
  __shared__ float redm[4], reds[4];
  int tid = threadIdx.x;
  int r   = tid >> 7;   // which of the 2 q-rows (wave-uniform)
  int k   = tid & 127;  // key index (lane-contiguous)
  int wid = tid >> 6;
  int g0  = blockIdx.x * 2;          // global (b,t,q) row pair base, 2048 rows
  int bt  = g0 >> 7;                 // b*T + t
  int b   = g0 >> 10;
  int q0  = b * 128 + (g0 & 127);    // row index into query [B*NQ]

  // stage the 2 query rows (coalesced, 128 floats)
  if (tid < 128) qrow[tid >> 6][tid & 63] = query[q0 * 64 + tid];
  __syncthreads();

  // inline q-projection: qv[r][d] = {C * (qrow[r] . Wq[:,d]), v[d]}
  for (int idx = tid; idx < 512; idx += 256) {
    int rr = idx >> 8;
    int d  = idx & 255;
    float acc = 0.f;
#pragma unroll
    for (int i = 0; i < 64; ++i) acc += qrow[rr][i] * Wq[i * 256 + d];
    qv[rr][d] = make_float2(acc * C_TANH, v[d]);
  }
  __syncthreads();

  const float* kp = k2 + bt * 256 * 128 + k;
  float acc = 0.f;
#pragma unroll 8
  for (int d = 0; d < 256; ++d) {
    float2 t = qv[r][d];                       // LDS broadcast
    float x  = t.x + kp[d * 128];              // coalesced global (L2-hot)
    float e  = __builtin_amdgcn_exp2f(x);
    acc += t.y * __builtin_amdgcn_rcpf(1.0f + e);
  }
  float s = -C_TANH * acc;  // logit pre-scaled by log2(e) for exp2 softmax

  // row max: wave butterfly then combine the row's 2 waves via LDS
  float m = s;
#pragma unroll
  for (int off = 32; off > 0; off >>= 1) m = fmaxf(m, __shfl_xor(m, off, 64));
  if ((tid & 63) == 0) redm[wid] = m;
  __syncthreads();
  float rowm = fmaxf(redm[r * 2], redm[r * 2 + 1]);

  float e = __builtin_amdgcn_exp2f(s - rowm);
  float ssum = e;
#pragma unroll
  for (int off = 32; off > 0; off >>= 1) ssum += __shfl_xor(ssum, off, 64);
  if ((tid & 63) == 0) reds[wid] = ssum;
  __syncthreads();
  float tot = reds[r * 2] + reds[r * 2 + 1];

  out[(g0 + r) * 128 + k] = e * __builtin_amdgcn_rcpf(tot);  // coalesced
}

extern "C" void kernel_launch(void* const* d_in, const int* in_sizes, int n_in,
                              void* d_out, int out_size, void* d_ws, size_t ws_size,
                              hipStream_t stream) {
  const float* query = (const float*)d_in[0];  // [2,128,64]
  const float* keys  = (const float*)d_in[1];  // [2,8,128,64]
  const float* Wq    = (const float*)d_in[2];  // [64,256]
  const float* Wk    = (const float*)d_in[3];  // [64,256]
  const float* bk    = (const float*)d_in[4];  // [256]
  const float* v     = (const float*)d_in[5];  // [256]
  float* out = (float*)d_out;                  // [2,8,128,128]

  float* k2 = (float*)d_ws;  // [16][256][128] = 524288 floats (2 MB)

  kproj_kernel<<<256, 256, 0, stream>>>(keys, Wk, bk, k2);
  score_kernel<<<1024, 256, 0, stream>>>(query, Wq, v, k2, out);
}

// Round 3
// 89.128 us; speedup vs baseline: 1.1632x; 1.0278x over previous
//
#include <hip/hip_runtime.h>

// Problem constants: B=2, T=8, NQ=128, NK=128, DIM_IN=64, DIM_OUT=256
// C = 2*log2(e): folds tanh's e^{2x} into exp2, and softmax's exp into exp2.
#define C_TANH 2.8853900817779268f

// Fused projection kernel, 512 blocks x 256 threads:
//   blocks [0,256):   k2[bt][d][k] = C*(keys[bt,k,:]@Wk[:,d] + bk[d]) (transposed)
//   blocks [256,512): q1[row][d]   = C*(query[row,:]@Wq[:,d])
__global__ __launch_bounds__(256) void proj_kernel(
    const float* __restrict__ query, const float* __restrict__ keys,
    const float* __restrict__ Wq, const float* __restrict__ Wk,
    const float* __restrict__ bk, float* __restrict__ q1,
    float* __restrict__ k2) {
  int bid = blockIdx.x;
  int d   = threadIdx.x;  // 256 output dims
  if (bid < 256) {
    // ---- k-projection: block = (bt, key-group-of-8) ----
    int bt = bid >> 4;
    int kg = bid & 15;
    __shared__ float4 krows4[128];  // 8 key rows x 64 floats = 2 KB
    if (threadIdx.x < 128)
      krows4[threadIdx.x] =
          ((const float4*)(keys + bt * 8192 + kg * 512))[threadIdx.x];
    __syncthreads();

    float acc[8];
    float bias = bk[d];
#pragma unroll
    for (int kk = 0; kk < 8; ++kk) acc[kk] = bias;
#pragma unroll 4
    for (int i4 = 0; i4 < 16; ++i4) {
      float wa = Wk[(i4 * 4 + 0) * 256 + d];   // coalesced across lanes
      float wb = Wk[(i4 * 4 + 1) * 256 + d];
      float wc = Wk[(i4 * 4 + 2) * 256 + d];
      float wd = Wk[(i4 * 4 + 3) * 256 + d];
#pragma unroll
      for (int kk = 0; kk < 8; ++kk) {
        float4 kr = krows4[kk * 16 + i4];      // wave-uniform b128 broadcast
        acc[kk] = fmaf(kr.x, wa, acc[kk]);
        acc[kk] = fmaf(kr.y, wb, acc[kk]);
        acc[kk] = fmaf(kr.z, wc, acc[kk]);
        acc[kk] = fmaf(kr.w, wd, acc[kk]);
      }
    }
#pragma unroll
    for (int kk = 0; kk < 8; ++kk)
      k2[(bt * 256 + d) * 128 + kg * 8 + kk] = acc[kk] * C_TANH;
  } else {
    // ---- q-projection: block = query row (B*NQ = 256 rows) ----
    int row = bid - 256;
    __shared__ float qrow[64];
    if (threadIdx.x < 64) qrow[threadIdx.x] = query[row * 64 + threadIdx.x];
    __syncthreads();
    float acc = 0.f;
#pragma unroll
    for (int i = 0; i < 64; ++i) acc += qrow[i] * Wq[i * 256 + d];
    q1[row * 256 + d] = acc * C_TANH;          // coalesced store
  }
}

// Score+softmax: one block = 4 q-rows; ONE WAVE per row (lane = k-pair).
// Each thread owns 2 adjacent keys -> float2 k2 loads, 2 indep acc chains.
// logits_k = -2 * sum_d v_d / (1 + exp2(q'_d + k'_dk))   (Sum v_d dropped:
// constant per row, softmax shift-invariant.) Softmax in exp2 domain; the
// row reduction is a pure 64-lane butterfly (no LDS, no __syncthreads).
__global__ __launch_bounds__(256) void score_kernel(
    const float* __restrict__ q1, const float* __restrict__ v,
    const float* __restrict__ k2, float* __restrict__ out) {
  __shared__ float2 qv[4][256];  // {q', v} per row -> ds_read_b64 broadcast
  int tid = threadIdx.x;
  int r   = tid >> 6;            // row within block == wave id
  int kk  = tid & 63;            // k-pair index (lane)
  int g0  = blockIdx.x * 4;      // global (b,t,q) row base; 2048 rows total
  int bt  = g0 >> 7;             // b*T + t   (4 rows never straddle bt)
  int b   = g0 >> 10;
  int q1base = b * 128 + (g0 & 127);  // q1 row (q1 has B*NQ = 256 rows)

  // stage 4 rows of {q', v}: 1024 entries, 4 per thread, coalesced
  for (int idx = tid; idx < 1024; idx += 256) {
    int rr = idx >> 8;
    int d  = idx & 255;
    qv[rr][d] = make_float2(q1[(q1base + rr) * 256 + d], v[d]);
  }
  __syncthreads();

  const float2* kp2 = (const float2*)(k2 + bt * 32768) + kk;
  float acc0 = 0.f, acc1 = 0.f;
#pragma unroll 8
  for (int d = 0; d < 256; ++d) {
    float2 qvv = qv[r][d];        // wave-uniform LDS broadcast (b64)
    float2 kv  = kp2[d * 64];     // coalesced 512B wave load (b64)
    float x0 = qvv.x + kv.x;      // pk_add candidates
    float x1 = qvv.x + kv.y;
    float e0 = __builtin_amdgcn_exp2f(x0);
    float e1 = __builtin_amdgcn_exp2f(x1);
    float r0 = __builtin_amdgcn_rcpf(1.0f + e0);
    float r1 = __builtin_amdgcn_rcpf(1.0f + e1);
    acc0 = fmaf(qvv.y, r0, acc0);
    acc1 = fmaf(qvv.y, r1, acc1);
  }
  float s0 = -C_TANH * acc0;      // logits pre-scaled by log2(e) for exp2
  float s1 = -C_TANH * acc1;

  // row max + sum: whole row lives in this wave -> butterfly only
  float m = fmaxf(s0, s1);
#pragma unroll
  for (int off = 32; off > 0; off >>= 1) m = fmaxf(m, __shfl_xor(m, off, 64));
  float e0 = __builtin_amdgcn_exp2f(s0 - m);
  float e1 = __builtin_amdgcn_exp2f(s1 - m);
  float ssum = e0 + e1;
#pragma unroll
  for (int off = 32; off > 0; off >>= 1) ssum += __shfl_xor(ssum, off, 64);
  float inv = __builtin_amdgcn_rcpf(ssum);

  ((float2*)(out + (g0 + r) * 128))[kk] = make_float2(e0 * inv, e1 * inv);
}

extern "C" void kernel_launch(void* const* d_in, const int* in_sizes, int n_in,
                              void* d_out, int out_size, void* d_ws, size_t ws_size,
                              hipStream_t stream) {
  const float* query = (const float*)d_in[0];  // [2,128,64]
  const float* keys  = (const float*)d_in[1];  // [2,8,128,64]
  const float* Wq    = (const float*)d_in[2];  // [64,256]
  const float* Wk    = (const float*)d_in[3];  // [64,256]
  const float* bk    = (const float*)d_in[4];  // [256]
  const float* v     = (const float*)d_in[5];  // [256]
  float* out = (float*)d_out;                  // [2,8,128,128]

  float* ws = (float*)d_ws;
  float* q1 = ws;            // 256*256   = 65536 floats (256 KB)
  float* k2 = ws + 65536;    // 16*256*128 = 524288 floats (2 MB)

  proj_kernel<<<512, 256, 0, stream>>>(query, keys, Wq, Wk, bk, q1, k2);
  score_kernel<<<512, 256, 0, stream>>>(q1, v, k2, out);
}